// Round 1
// 671.752 us; speedup vs baseline: 1.6510x; 1.6510x over previous
//
#include <hip/hip_runtime.h>
#include <hip/hip_bf16.h>
#include <stdint.h>

typedef _Float16 f16;
typedef _Float16 f16x2 __attribute__((ext_vector_type(2)));
typedef _Float16 f16x4 __attribute__((ext_vector_type(4)));
typedef _Float16 f16x8 __attribute__((ext_vector_type(8)));
typedef float f32x4 __attribute__((ext_vector_type(4)));
typedef int   i32x4 __attribute__((ext_vector_type(4)));

#define T_STEPS 512
#define BATCH   128
#define DD      512
#define LOG2E   1.44269504088896f

// workspace layout (bytes)
#define XP_OFF  0                          // f16 Xproj' [512][128][512] = 67,108,864
#define WF_OFF  (67108864)                 // f16 W_in  [512][512]      =    524,288
#define WHQ_OFF (67108864 + 524288)        // i8  W_h frag-packed       =    262,144
#define SC_OFF  (67108864 + 524288 + 262144) // f32 row scales2 [512]   =      2,048

__device__ __forceinline__ f16x2 pk(float a, float b) {
    return __builtin_bit_cast(f16x2, __builtin_amdgcn_cvt_pkrtz(a, b));
}

__device__ __forceinline__ float fast_exp2(float x) {
#if __has_builtin(__builtin_amdgcn_exp2f)
    return __builtin_amdgcn_exp2f(x);
#else
    return exp2f(x);
#endif
}

__device__ __forceinline__ float fast_rcp(float x) {
#if __has_builtin(__builtin_amdgcn_rcpf)
    return __builtin_amdgcn_rcpf(x);
#else
    return 1.0f / x;
#endif
}

__device__ __forceinline__ uint32_t pack_u8(float s, int pos, uint32_t old) {
#if __has_builtin(__builtin_amdgcn_cvt_pk_u8_f32)
    return __builtin_amdgcn_cvt_pk_u8_f32(s, pos, old);
#else
    return old | (((uint32_t)(int)s & 0xFF) << (8 * pos));
#endif
}

#define GLDS(g, l) __builtin_amdgcn_global_load_lds(                               \
        (const __attribute__((address_space(1))) void*)(g),                        \
        (__attribute__((address_space(3))) void*)(l), 16, 0, 0)

// ---------------------------------------------------------------- prep: Wf (f16 W_in)
__global__ __launch_bounds__(256) void prep_kernel(
        const float* __restrict__ Win, f16* __restrict__ Wf) {
    int idx = blockIdx.x * 256 + threadIdx.x;
    if (idx < 262144) Wf[idx] = (f16)Win[idx];
}

// ------------------------------------------- quantize W_h to i8, frag-packed, per-row scale
// one wave per output row o. A-frag packing: byte index
//   ((rt*8+ks)*64 + l)*16 + j  ->  W_h[out][k],  rt = o>>4
//   out = rt*16+(l&15), k = ks*64+(l>>4)*16+j
// scales2[o] = -log2e * m/(127*127): epilogue computes t = acc*sc2 + xp2 = -log2e*v.
__global__ __launch_bounds__(64) void quant_kernel(
        const float* __restrict__ Wh, char* __restrict__ Whq, float* __restrict__ scales) {
    const int o = blockIdx.x, t = threadIdx.x;
    const float* row = Wh + (size_t)o * 512;
    float v[8];
    float m = 0.f;
#pragma unroll
    for (int j = 0; j < 8; j++) { v[j] = row[t * 8 + j]; m = fmaxf(m, fabsf(v[j])); }
#pragma unroll
    for (int off = 32; off > 0; off >>= 1) m = fmaxf(m, __shfl_xor(m, off));
    if (t == 0) scales[o] = -LOG2E * m * (1.0f / (127.0f * 127.0f));
    const float inv = 127.0f / m;
    const int rt = o >> 4, rl = o & 15;
    const int k0 = t * 8;
    const int ks = k0 >> 6, qq = (k0 >> 4) & 3, j0 = k0 & 15;
    const int l = qq * 16 + rl;
    char* dst = Whq + ((size_t)((rt * 8 + ks) * 64 + l)) * 16 + j0;
#pragma unroll
    for (int j = 0; j < 8; j++) dst[j] = (char)rintf(v[j] * inv);
}

// ------------------------------------------------- Xproj' = -log2e*(X @ Win^T + b_h), f16
// 128M x 256N tile, BK=32. A (f32) staged via global_load_lds with XOR chunk swizzle
// (linear LDS dest + inverse-swizzled per-lane global source + swizzled ds_read: rule #21).
// B (f16) staged linearly (64B rows naturally spread banks). 8 waves = (wm 0..1)x(wn 0..3),
// each 64x64 out via acc[4][4] 16x16x32 f16 MFMA (fragment layout identical to verified v1).
// Double-buffered, ONE barrier/iter (stage into buf read two phases ago).
__global__ __launch_bounds__(512, 4) void gemm_kernel(
        const float* __restrict__ X, const f16* __restrict__ Wf,
        const float* __restrict__ bias, f16* __restrict__ Xp) {
    const int tid = threadIdx.x;
    const int l = tid & 63, w = tid >> 6;
    const int q = l >> 4, rl = l & 15;
    const int wm = w >> 2, wn = w & 3;
    const int m_blk = blockIdx.y * 128;
    const int n_blk = blockIdx.x * 256;

    __shared__ __align__(16) float As[2][128 * 32];   // 2 x 16 KB
    __shared__ __align__(16) f16   Bs[2][256 * 32];   // 2 x 16 KB

    // staging sources: per-lane, advance by k each iter.
    // A instr c: row = w*16 + c*8 + (l>>3); source 16B-chunk = (l&7) ^ (l>>3)
    const float* aSrc[2];
#pragma unroll
    for (int c = 0; c < 2; c++)
        aSrc[c] = X + (size_t)(m_blk + w * 16 + c * 8 + (l >> 3)) * 512
                    + (((l & 7) ^ (l >> 3)) << 2);
    // B instr c: row = w*32 + c*16 + (l>>2); chunk l&3 (linear)
    const f16* bSrc[2];
#pragma unroll
    for (int c = 0; c < 2; c++)
        bSrc[c] = Wf + (size_t)(n_blk + w * 32 + c * 16 + (l >> 2)) * 512
                     + ((l & 3) << 3);

    f32x4 acc[4][4] = {};
    // per-lane constant swizzled chunk offsets for A reads (float units)
    const int sw0 = (((2 * q)     ^ (rl & 7)) << 2);
    const int sw1 = (((2 * q + 1) ^ (rl & 7)) << 2);

    // prologue: stage tile 0
#pragma unroll
    for (int c = 0; c < 2; c++) GLDS(aSrc[c], &As[0][(w * 16 + c * 8) * 32]);
#pragma unroll
    for (int c = 0; c < 2; c++) GLDS(bSrc[c], &Bs[0][(w * 32 + c * 16) * 32]);

    for (int t = 0; t < 16; ++t) {
        const int cur = t & 1;
        __syncthreads();   // drains own vmcnt -> tile cur ready; also fences reads of cur^1
        if (t < 15) {      // stage next tile into the buffer everyone finished reading
            const int kf = (t + 1) * 32;
#pragma unroll
            for (int c = 0; c < 2; c++) GLDS(aSrc[c] + kf, &As[cur ^ 1][(w * 16 + c * 8) * 32]);
#pragma unroll
            for (int c = 0; c < 2; c++) GLDS(bSrc[c] + kf, &Bs[cur ^ 1][(w * 32 + c * 16) * 32]);
        }
        f16x8 af[4], bf[4];
#pragma unroll
        for (int i = 0; i < 4; i++) {
            const int row = wm * 64 + i * 16 + rl;
            const float4 h0 = *(const float4*)&As[cur][row * 32 + sw0];
            const float4 h1 = *(const float4*)&As[cur][row * 32 + sw1];
            f16x2 p0 = pk(h0.x, h0.y), p1 = pk(h0.z, h0.w);
            f16x2 p2 = pk(h1.x, h1.y), p3 = pk(h1.z, h1.w);
            f16x8 tv;
            tv[0] = p0[0]; tv[1] = p0[1]; tv[2] = p1[0]; tv[3] = p1[1];
            tv[4] = p2[0]; tv[5] = p2[1]; tv[6] = p3[0]; tv[7] = p3[1];
            af[i] = tv;
        }
#pragma unroll
        for (int j = 0; j < 4; j++) {
            const int row = wn * 64 + j * 16 + rl;
            bf[j] = *(const f16x8*)&Bs[cur][row * 32 + q * 8];
        }
#pragma unroll
        for (int i = 0; i < 4; i++)
#pragma unroll
            for (int j = 0; j < 4; j++)
                acc[i][j] = __builtin_amdgcn_mfma_f32_16x16x32_f16(af[i], bf[j], acc[i][j], 0, 0, 0);
    }
#pragma unroll
    for (int j = 0; j < 4; j++) {
        const int n = n_blk + wn * 64 + j * 16 + rl;
        const float bn = bias[n];
#pragma unroll
        for (int i = 0; i < 4; i++)
#pragma unroll
            for (int r = 0; r < 4; r++) {
                const int m = m_blk + wm * 64 + i * 16 + q * 4 + r;
                Xp[(size_t)m * 512 + n] = (f16)(-LOG2E * (acc[i][j][r] + bn));
            }
    }
}

// ----------------------------------------------------------------- recurrence (i8 MFMA)
// C[out][batch] = Wq @ hq^T per step. 8 WGs x 16 batches; now 16 waves (1024 thr),
// wave w owns rows [32w,32w+32) = row-tiles rt in {2w, 2w+1}. 4 waves/SIMD (was 2) so
// epilogue trans/VALU and LDS latency hide under other waves' MFMAs. i8 A-frags
// register-resident (af = 64 VGPR; total ~115 <= 128 for full-block residency).
// h^T in LDS in exact B-fragment lane order. Epilogue per output (VALU-minimal):
// t = fma(accf, sc2, xp2); e = exp2(t); eq = fma(e,1/127,1/127); r = rcp(eq) = 127*sigmoid.
__global__ __launch_bounds__(1024) void rnn_kernel(
        const char* __restrict__ Whq, const float* __restrict__ scales,
        const f16* __restrict__ Xp, float* __restrict__ out) {
    const int wg = blockIdx.x;          // 0..7
    const int tid = threadIdx.x;
    const int l = tid & 63, w = tid >> 6;   // w in 0..15
    const int bl = l & 15;              // batch lane (N / C col)
    const int q = l >> 4;               // k-quad / C row quad
    const int b = wg * 16 + bl;

    __shared__ __align__(16) uint32_t hT[2][2048];   // 8 KB per buffer, frag-ordered

    // register-resident i8 A-fragments: af[mt][ks], 4 dwords each = 64 regs
    i32x4 af[2][8];
    {
        const i32x4* wp = (const i32x4*)Whq;
#pragma unroll
        for (int mt = 0; mt < 2; mt++)
#pragma unroll
            for (int ks = 0; ks < 8; ks++)
                af[mt][ks] = wp[((w * 2 + mt) * 8 + ks) * 64 + l];
    }
    // per-lane output-row scales (pre-folded with -log2e/127^2)
    float sc[2][4];
#pragma unroll
    for (int mt = 0; mt < 2; mt++)
#pragma unroll
        for (int r = 0; r < 4; r++)
            sc[mt][r] = scales[w * 32 + mt * 16 + q * 4 + r];

    for (int i = tid; i < 2048; i += 1024) hT[0][i] = 0u;
    __syncthreads();

    const f16* xpb = Xp + (size_t)b * 512 + w * 32 + q * 4;
    f16x4 xn[2];
    xn[0] = *(const f16x4*)(xpb);
    xn[1] = *(const f16x4*)(xpb + 16);

    const float K127 = 1.0f / 127.0f;
    for (int t = 0; t < T_STEPS; t++) {
        f16x4 xc[2];
        xc[0] = xn[0]; xc[1] = xn[1];
        const size_t tn = (size_t)(t < T_STEPS - 1 ? t + 1 : t) * (BATCH * 512);
        xn[0] = *(const f16x4*)(xpb + tn);
        xn[1] = *(const f16x4*)(xpb + tn + 16);

        const int rb = t & 1;
        i32x4 acc[2] = {};
        const uint32_t* hrow = &hT[rb][l * 4];
#pragma unroll
        for (int ks = 0; ks < 8; ks++) {
            i32x4 bfr = *(const i32x4*)(hrow + ks * 256);
            acc[0] = __builtin_amdgcn_mfma_i32_16x16x64_i8(af[0][ks], bfr, acc[0], 0, 0, 0);
            acc[1] = __builtin_amdgcn_mfma_i32_16x16x64_i8(af[1][ks], bfr, acc[1], 0, 0, 0);
        }
#pragma unroll
        for (int mt = 0; mt < 2; mt++) {
            uint32_t pkq = 0;
#pragma unroll
            for (int r = 0; r < 4; r++) {
                float tt = fmaf((float)acc[mt][r], sc[mt][r], (float)xc[mt][r]);
                float e  = fast_exp2(tt);                // e^{-v}
                float eq = fmaf(e, K127, K127);          // (1+e^{-v})/127
                float sg = fast_rcp(eq) + 0.5f;          // 127*sigmoid + 0.5
                pkq = pack_u8(sg, r, pkq);
            }
            hT[1 - rb][(w * 2 + mt) * 64 + bl * 4 + q] = pkq;
        }
        __syncthreads();
    }
    // final h: read back this lane's own dwords, dequantize i8/127 -> f32
#pragma unroll
    for (int mt = 0; mt < 2; mt++) {
        uint32_t pkq = hT[T_STEPS & 1][(w * 2 + mt) * 64 + bl * 4 + q];
        float4 o;
        o.x = (float)((pkq      ) & 0xFF) * K127;
        o.y = (float)((pkq >>  8) & 0xFF) * K127;
        o.z = (float)((pkq >> 16) & 0xFF) * K127;
        o.w = (float)((pkq >> 24) & 0xFF) * K127;
        *(float4*)(out + (size_t)b * 512 + w * 32 + mt * 16 + q * 4) = o;
    }
}

extern "C" void kernel_launch(void* const* d_in, const int* in_sizes, int n_in,
                              void* d_out, int out_size, void* d_ws, size_t ws_size,
                              hipStream_t stream) {
    const float* X   = (const float*)d_in[0];
    const float* Win = (const float*)d_in[1];
    const float* Wh  = (const float*)d_in[2];
    const float* bh  = (const float*)d_in[3];
    float* out = (float*)d_out;
    char* ws = (char*)d_ws;
    f16* Xp      = (f16*)(ws + XP_OFF);
    f16* Wf      = (f16*)(ws + WF_OFF);
    char* Whq    = (char*)(ws + WHQ_OFF);
    float* Sc    = (float*)(ws + SC_OFF);

    prep_kernel<<<1024, 256, 0, stream>>>(Win, Wf);
    quant_kernel<<<512, 64, 0, stream>>>(Wh, Whq, Sc);
    gemm_kernel<<<dim3(2, 512), 512, 0, stream>>>(X, Wf, bh, Xp);
    rnn_kernel<<<8, 1024, 0, stream>>>(Whq, Sc, Xp, out);
}